// Round 11
// baseline (1621.780 us; speedup 1.0000x reference)
//
#include <hip/hip_runtime.h>
#include <stdint.h>

// LSTM B=256,T=512,F=32,U=350; gates i,f,g(relu),o; h=o*relu(c); out=h.dw+db
//
// R19: incremental per-block h consumption (R18 base, 885us).
//  R18 postmortem: x off the vmcnt head = null -> load ordering exhausted.
//  Remaining structure: all-or-nothing spin puts the WHOLE consumer body
//  (22 loads + 44 MFMAs + gates, ~600-800cy) serially behind the slowest
//  of 22 producers every step.
//  Change: consume blocks as tag pairs land. Per poll round: one vector
//  tag poll + __ballot -> ready mask; issue loads for all newly-ready
//  blocks (pipelined), then MFMA them; repeat until done==0x7FF. Steady
//  state round 1 == R18 path; with a laggard, post-laggard tail becomes
//  detect + 1 block load + 4 MFMA + gates. Also spreads L2 load bursts.
//  Distress->mirror: on transition dump wout/wout_prev (tags t, t-1) as
//  before; mm mode fills REMAINING blocks from mirror with per-block
//  tag-in-word validation. Protocol/proofs unchanged from R11/R14/R18.

#define T_   512
#define F_   32
#define U_   350
#define G4   1400
#define NGRP 16
#define NB   16
#define NCB  11
#define KC   12
#define NT   88
#define HSLOTUS 5632    // ushorts per bf16 fast slot (11 blk * 512)
#define SLOTW   5632    // u32 words per mirror slot (R10 layout)

typedef __attribute__((ext_vector_type(8))) short  short8;
typedef __attribute__((ext_vector_type(4))) short  short4_;
typedef __attribute__((ext_vector_type(4))) float  float4_;
typedef unsigned long long u64t;

__device__ __forceinline__ short f2bf(float f) {
  union { float f; uint32_t u; } v; v.f = f;
  return (short)((v.u + 0x7FFFu + ((v.u >> 16) & 1u)) >> 16);
}

// ---- workspace layout (bytes) ----
#define SZ_W     (NT*KC*64*8*2u)                        // 1,081,344
#define OFF_XBF  (SZ_W)
#define SZ_XBF   (256u*T_*F_*2u)                        // 8,388,608
#define OFF_HBUF (OFF_XBF + SZ_XBF)
#define SZ_HBUF  (NGRP*2u*HSLOTUS*2u)                   // 360,448
#define OFF_HMIR (OFF_HBUF + SZ_HBUF)
#define SZ_HMIR  (NGRP*2u*SLOTW*4u)                     // 720,896
#define OFF_TAG  (OFF_HMIR + SZ_HMIR)
#define SZ_TAG   (NGRP*2u*32u*4u)                       // 4,096
#define OFF_FLG  (OFF_TAG + SZ_TAG)
#define SZ_FLG   (NGRP*16u*4u)                          // 1,024
#define OFF_WP   (OFF_FLG + SZ_FLG)
#define SZ_WP    (NGRP*NCB*NB*T_*4u)                    // 5,767,168

// ---- prep: W_swz[kc][tile][lane][8] bf16 in MFMA B-fragment order ----
__global__ void prep_w(const float* __restrict__ kern,
                       const float* __restrict__ rk,
                       const float* __restrict__ bias,
                       short* __restrict__ wswz) {
  const int tile = blockIdx.x, lane = threadIdx.x;
  const int g = tile / 22, jt = tile % 22;
  const int colg = jt * 16 + (lane & 15);
  const int src = g * U_ + colg;
  const bool valid = (colg < U_);
  const int kbase = (lane >> 4) * 8;
  for (int kc = 0; kc < KC; ++kc) {
    short8 pack;
    #pragma unroll
    for (int jj = 0; jj < 8; ++jj) {
      int k = kc * 32 + kbase + jj;
      float v = 0.f;
      if (valid) {
        if (k < F_)            v = kern[k * G4 + src];
        else if (k < F_ + U_)  v = rk[(k - F_) * G4 + src];
        else if (k == F_ + U_) v = bias[src];
      }
      pack[jj] = f2bf(v);
    }
    *(short8*)(wswz + (((size_t)kc * NT + tile) * 64 + lane) * 8) = pack;
  }
}

// ---- prep: x f32 -> bf16 ([b][t][f], contiguous 16B A-frag loads) ----
__global__ void prep_x(const float* __restrict__ x, short* __restrict__ xbf) {
  int i = (blockIdx.x * 256 + threadIdx.x) * 4;
  float4_ v = *(const float4_*)(x + i);
  short4_ o;
  #pragma unroll
  for (int jj = 0; jj < 4; ++jj) o[jj] = f2bf(v[jj]);
  *(short4_*)(xbf + i) = o;
}

// ---- init: slot1 = h_{-1}=0 tag 0 (bias col 350 = 1.0); tags; flag ----
__global__ void init_all(unsigned short* __restrict__ hb16,
                         uint32_t* __restrict__ hmir32,
                         uint32_t* __restrict__ tagbuf,
                         uint32_t* __restrict__ flagbuf) {
  int i = blockIdx.x * 256 + threadIdx.x;            // 0 .. NGRP*5632-1
  int grp = i / HSLOTUS, rem = i % HSLOTUS;
  // fast bf16 slot1: rem = blk*512 + (quad_c*16+row)*8 + cpos
  {
    int blk = rem >> 9, quadc = (rem >> 7) & 3, cpos = rem & 7;
    int col = blk * 32 + quadc * 8 + cpos;
    hb16[(size_t)(grp * 2 + 1) * HSLOTUS + rem] =
        (col == 350) ? (unsigned short)0x3F80 : 0;
  }
  // mirror slot1 (R10 tag-in-word layout)
  {
    int blkm = rem >> 8, off = rem & 255;
    int fi = blkm >> 1, fk2 = blkm & 1, fquadc = off >> 6;
    int fk1 = (off >> 1) & 1, fb = off & 1;
    int fcol = fi * 32 + fquadc * 8 + fk2 * 4 + fk1 * 2 + fb;
    hmir32[(size_t)(grp * 2 + 1) * SLOTW + rem] =
        (fcol == 350) ? 0x3F800000u : 0u;
  }
  if (rem < 32) {
    tagbuf[(size_t)(grp * 2 + 0) * 32 + rem] = 0u;
    tagbuf[(size_t)(grp * 2 + 1) * 32 + rem] = 0u;
  }
  if (rem == 0) flagbuf[grp * 16] = 0u;
}

// ---- main: persistent, 2 decoupled waves per block, weights in regs ----
__global__ __launch_bounds__(128)
__attribute__((amdgpu_waves_per_eu(1, 1)))
void lstm_kernel(const short* __restrict__ xbf, const short* __restrict__ wswz,
                 unsigned short* __restrict__ hb16, uint32_t* __restrict__ hmir32,
                 uint32_t* __restrict__ tagbuf, uint32_t* __restrict__ flagbuf,
                 const float* __restrict__ dense_w, float* __restrict__ wpart) {
  __shared__ float lds_part[2][T_][16];   // 64 KB dense-head partials

  const int tid  = threadIdx.x;
  const int lane = tid & 63;
  const int wv   = tid >> 6;            // 0..1
  const int l15  = lane & 15;
  const int quad = lane >> 4;
  const int grp  = blockIdx.x & 15;     // same-XCD heuristic (fast path only)
  const int j    = blockIdx.x >> 4;     // 0..10
  const int tileg = 2 * j + wv;         // this wave's col tile 0..21

  // weights -> registers ONCE
  short8 wreg[4][KC];
  #pragma unroll
  for (int g = 0; g < 4; ++g)
    #pragma unroll
    for (int kc = 0; kc < KC; ++kc)
      wreg[g][kc] = *(const short8*)(wswz +
          (((size_t)kc * NT + (g * 22 + tileg)) * 64 + lane) * 8);

  const int col = tileg * 16 + l15;               // gate-relative col 0..351
  const float dwv = (col < U_) ? dense_w[col] : 0.f;
  float cst[4] = {0.f, 0.f, 0.f, 0.f};

  // fast bf16 producer: ushort idx = pbase_us + r*8 (rows quad*4+r)
  const int pblk = col >> 5, pc32 = col & 31;
  const int pbase_us = pblk * 512 + ((pc32 >> 3) * 16 + quad * 4) * 8 + (pc32 & 7);
  // mirror (R10 tag-in-word) offset, +r*4 per row
  const int colrem = col & 31;
  const int fastoff = (((col >> 5) * 2 + ((colrem >> 2) & 1)) * 256)
                    + (((colrem >> 3) * 16 + quad * 4) * 4)
                    + (((colrem >> 1) & 1) * 2) + (col & 1);

  const short* xrow = xbf + ((size_t)(grp * NB + l15) * T_) * F_ + quad * 8;
  unsigned short* hbb = hb16 + (size_t)grp * 2 * HSLOTUS;
  uint32_t* hm  = hmir32 + (size_t)grp * 2 * SLOTW;
  uint32_t* tgg = tagbuf + (size_t)grp * 2 * 32;
  uint32_t* flagp = flagbuf + grp * 16;
  const int tagidx = (lane < 22) ? lane : 31;     // word31: always 0

  bool mm = false;                                 // mirror (degraded) mode
  const short hs_init = (col == 350) ? (short)0x3F80 : 0;
  uint32_t wout[4], wout_prev[4];
  #pragma unroll
  for (int r = 0; r < 4; ++r)
    wout[r] = wout_prev[r] = ((uint32_t)(unsigned short)hs_init) << 16;

  // x software pipeline prologue: load t=0 (single cold stall, once)
  short8 axf = *(const short8*)(xrow);

  #pragma unroll 1
  for (int t = 0; t < T_; ++t) {
    const uint32_t want = (uint32_t)t;
    const uint32_t* tgr = tgg + (size_t)((t + 1) & 1) * 32;

    // kc=0 (x-only) MFMA — h-independent; axf loaded last iter post-publish
    float4_ acc[4];
    #pragma unroll
    for (int g = 0; g < 4; ++g) {
      float4_ z = (float4_){0.f, 0.f, 0.f, 0.f};
      acc[g] = __builtin_amdgcn_mfma_f32_16x16x32_bf16(axf, wreg[g][0], z, 0, 0, 0);
    }

    // ---- incremental per-block consume: poll -> load ready -> MFMA ----
    const u64t* hq = (const u64t*)(hbb + (size_t)((t + 1) & 1) * HSLOTUS)
                   + (size_t)lane * 2;
    uint32_t done = 0;                 // 11-bit mask of folded blocks
    int tries = 0;
    while (done != 0x7FFu) {
      if (!mm) {
        uint32_t tv = __hip_atomic_load(tgr + tagidx, __ATOMIC_RELAXED,
                                        __HIP_MEMORY_SCOPE_AGENT);
        u64t rdy = __ballot((int)(lane >= 22 || tv == want));
        uint32_t newm = 0;
        short8 afr[11];
        #pragma unroll
        for (int i = 0; i < 11; ++i) {
          if (!((done >> i) & 1u) && (((rdy >> (2 * i)) & 3ull) == 3ull)) {
            union { u64t q[2]; short8 s; } u;
            u.q[0] = __hip_atomic_load(hq + (size_t)i * 128,     __ATOMIC_RELAXED, __HIP_MEMORY_SCOPE_AGENT);
            u.q[1] = __hip_atomic_load(hq + (size_t)i * 128 + 1, __ATOMIC_RELAXED, __HIP_MEMORY_SCOPE_AGENT);
            afr[i] = u.s;
            newm |= 1u << i;
          }
        }
        #pragma unroll
        for (int i = 0; i < 11; ++i)
          if ((newm >> i) & 1u)
            #pragma unroll
            for (int g = 0; g < 4; ++g)
              acc[g] = __builtin_amdgcn_mfma_f32_16x16x32_bf16(afr[i], wreg[g][i + 1], acc[g], 0, 0, 0);
        done |= newm;
        if (done == 0x7FFu) break;
        ++tries;
        if ((tries & 63) == 0) {                    // poll distress (system)
          uint32_t f = __hip_atomic_load(flagp, __ATOMIC_RELAXED,
                                         __HIP_MEMORY_SCOPE_SYSTEM);
          if (f) mm = true;
        }
        if (tries == 16384) {                       // raise distress
          if (lane == 0)
            __hip_atomic_store(flagp, 1u, __ATOMIC_RELAXED,
                               __HIP_MEMORY_SCOPE_SYSTEM);
          mm = true;
        }
        if (mm) {
          // dump last two h vectors (self-validating tag-in-word)
          uint32_t* md1 = hm + (size_t)((t + 1) & 1) * SLOTW + fastoff; // tag t
          uint32_t* md0 = hm + (size_t)(t & 1) * SLOTW + fastoff;       // tag t-1
          #pragma unroll
          for (int r = 0; r < 4; ++r) {
            __hip_atomic_store(md1 + r * 4, wout[r], __ATOMIC_RELAXED,
                               __HIP_MEMORY_SCOPE_AGENT);
            __hip_atomic_store(md0 + r * 4, wout_prev[r], __ATOMIC_RELAXED,
                               __HIP_MEMORY_SCOPE_AGENT);
          }
        }
      } else {
        // mirror mode: fill REMAINING blocks, per-block tag-in-word check
        const u64t* mq = (const u64t*)(hm + (size_t)((t + 1) & 1) * SLOTW)
                       + (size_t)lane * 2;
        const uint32_t tag16 = want & 0xFFFFu;
        #pragma unroll
        for (int i = 0; i < 11; ++i) {
          if ((done >> i) & 1u) continue;
          u64t q0 = __hip_atomic_load(mq + (size_t)(2 * i) * 128,     __ATOMIC_RELAXED, __HIP_MEMORY_SCOPE_AGENT);
          u64t q1 = __hip_atomic_load(mq + (size_t)(2 * i) * 128 + 1, __ATOMIC_RELAXED, __HIP_MEMORY_SCOPE_AGENT);
          u64t q2 = __hip_atomic_load(mq + (size_t)(2 * i + 1) * 128,     __ATOMIC_RELAXED, __HIP_MEMORY_SCOPE_AGENT);
          u64t q3 = __hip_atomic_load(mq + (size_t)(2 * i + 1) * 128 + 1, __ATOMIC_RELAXED, __HIP_MEMORY_SCOPE_AGENT);
          uint32_t bad = 0;
          bad |= ((uint32_t)q0 ^ tag16) | ((uint32_t)(q0 >> 32) ^ tag16);
          bad |= ((uint32_t)q1 ^ tag16) | ((uint32_t)(q1 >> 32) ^ tag16);
          bad |= ((uint32_t)q2 ^ tag16) | ((uint32_t)(q2 >> 32) ^ tag16);
          bad |= ((uint32_t)q3 ^ tag16) | ((uint32_t)(q3 >> 32) ^ tag16);
          if ((bool)__all((int)((bad & 0xFFFFu) == 0))) {
            union { uint32_t w[4]; short8 s; } u;
            u.w[0] = ((uint32_t)q0 >> 16) | ((uint32_t)(q0 >> 32) & 0xFFFF0000u);
            u.w[1] = ((uint32_t)q1 >> 16) | ((uint32_t)(q1 >> 32) & 0xFFFF0000u);
            u.w[2] = ((uint32_t)q2 >> 16) | ((uint32_t)(q2 >> 32) & 0xFFFF0000u);
            u.w[3] = ((uint32_t)q3 >> 16) | ((uint32_t)(q3 >> 32) & 0xFFFF0000u);
            #pragma unroll
            for (int g = 0; g < 4; ++g)
              acc[g] = __builtin_amdgcn_mfma_f32_16x16x32_bf16(u.s, wreg[g][i + 1], acc[g], 0, 0, 0);
            done |= 1u << i;
          }
        }
      }
    }

    // update: lane covers rows quad*4+r at its col; gates in registers
    unsigned short* hwp = hbb + (size_t)(t & 1) * HSLOTUS + pbase_us;
    const uint32_t otag = (uint32_t)(t + 1);
    float hn[4];
    #pragma unroll
    for (int r = 0; r < 4; ++r) {
      float ig = __builtin_amdgcn_rcpf(1.f + __expf(-acc[0][r]));
      float fg = __builtin_amdgcn_rcpf(1.f + __expf(-acc[1][r]));
      float gg = fmaxf(acc[2][r], 0.f);
      float og = __builtin_amdgcn_rcpf(1.f + __expf(-acc[3][r]));
      float cn = fg * cst[r] + ig * gg;
      cst[r] = cn;
      hn[r] = og * fmaxf(cn, 0.f);
      short hs = f2bf(hn[r]);
      if (col == 350) hs = (short)0x3F80;        // bias-row input stays 1.0
      else if (col == 351) hs = 0;
      wout_prev[r] = wout[r];
      wout[r] = (((uint32_t)(unsigned short)hs) << 16) | (otag & 0xFFFFu);
      hwp[r * 8] = (unsigned short)hs;           // fast bf16 data store (L2)
    }
    // publish tag with RELEASE (drains the 4 data stores first)
    if (lane == 0)
      __hip_atomic_store(tgg + (size_t)(t & 1) * 32 + tileg, otag,
                         __ATOMIC_RELEASE, __HIP_MEMORY_SCOPE_WORKGROUP);

    // x prefetch for t+1 POST-publish (atomic form pins placement)
    short8 axf_nx;
    {
      const int tn = (t + 1 < T_) ? (t + 1) : 0;
      const u64t* xq = (const u64t*)(xrow + tn * F_);
      union { u64t q[2]; short8 s; } ux;
      ux.q[0] = __hip_atomic_load(xq,     __ATOMIC_RELAXED, __HIP_MEMORY_SCOPE_AGENT);
      ux.q[1] = __hip_atomic_load(xq + 1, __ATOMIC_RELAXED, __HIP_MEMORY_SCOPE_AGENT);
      axf_nx = ux.s;
    }

    // degraded mode: also keep the coherent mirror current
    if (mm) {
      uint32_t* hwrm = hm + (size_t)(t & 1) * SLOTW + fastoff;
      #pragma unroll
      for (int r = 0; r < 4; ++r)
        __hip_atomic_store(hwrm + r * 4, wout[r], __ATOMIC_RELAXED,
                           __HIP_MEMORY_SCOPE_AGENT);
    }

    // dense head AFTER publish (off the recurrence; wave has slack here)
    #pragma unroll
    for (int r = 0; r < 4; ++r) {
      float s = hn[r] * dwv;
      s += __shfl_xor(s, 1); s += __shfl_xor(s, 2);
      s += __shfl_xor(s, 4); s += __shfl_xor(s, 8);
      if (l15 == 0) lds_part[wv][t][quad * 4 + r] = s;
    }

    axf = axf_nx;                                  // pipeline shift
  }

  // bulk-store dense partials (once)
  __syncthreads();
  float* wp = wpart + ((size_t)(grp * NCB + j) * NB) * T_;
  for (int i = tid; i < NB * T_; i += 128) {
    int t = i & (T_ - 1), row = i >> 9;
    wp[(size_t)row * T_ + t] = lds_part[0][t][row] + lds_part[1][t][row];
  }
}

// ---- final: out[b,t] = db + sum_j wpart[grp][j][row][t] ----
__global__ void reduce_out(const float* __restrict__ wpart,
                           const float* __restrict__ dense_b,
                           float* __restrict__ out) {
  int i = blockIdx.x * 256 + threadIdx.x;   // i = b*T + t
  int b = i >> 9, t = i & 511;
  int grp = b >> 4, row = b & 15;
  float s = dense_b[0];
  #pragma unroll
  for (int j = 0; j < NCB; ++j)
    s += wpart[(((size_t)grp * NCB + j) * NB + row) * T_ + t];
  out[i] = s;
}

extern "C" void kernel_launch(void* const* d_in, const int* in_sizes, int n_in,
                              void* d_out, int out_size, void* d_ws, size_t ws_size,
                              hipStream_t stream) {
  const float* x    = (const float*)d_in[0];
  const float* kern = (const float*)d_in[1];
  const float* rk   = (const float*)d_in[2];
  const float* bias = (const float*)d_in[3];
  const float* dw   = (const float*)d_in[4];
  const float* db   = (const float*)d_in[5];
  float* out = (float*)d_out;

  char* ws = (char*)d_ws;
  short*          wswz   = (short*)(ws);
  short*          xbf    = (short*)(ws + OFF_XBF);
  unsigned short* hb16   = (unsigned short*)(ws + OFF_HBUF);
  uint32_t*       hmir32 = (uint32_t*)(ws + OFF_HMIR);
  uint32_t*       tagbuf = (uint32_t*)(ws + OFF_TAG);
  uint32_t*       flagbuf= (uint32_t*)(ws + OFF_FLG);
  float*          wpart  = (float*)(ws + OFF_WP);

  prep_w<<<NT, 64, 0, stream>>>(kern, rk, bias, wswz);
  prep_x<<<(256 * T_ * F_) / (256 * 4), 256, 0, stream>>>(x, xbf);
  init_all<<<(NGRP * HSLOTUS) / 256, 256, 0, stream>>>(hb16, hmir32, tagbuf, flagbuf);
  lstm_kernel<<<NGRP * NCB, 128, 0, stream>>>(xbf, wswz, hb16, hmir32, tagbuf,
                                              flagbuf, dw, wpart);
  reduce_out<<<(256 * T_) / 256, 256, 0, stream>>>(wpart, db, out);
}

// Round 13
// 1051.855 us; speedup vs baseline: 1.5418x; 1.5418x over previous
//
#include <hip/hip_runtime.h>
#include <stdint.h>

// LSTM B=256,T=512,F=32,U=350; gates i,f,g(relu),o; h=o*relu(c); out=h.dw+db
//
// R21 == R20 resubmission (container failed twice with no diagnostics; no
//  new instruction forms vs passing R18 -> judged infra flake, not kernel).
// R20: R18 base (883us, best) + three micro-cuts on the serial ring period.
//  R19 postmortem: incremental consume regressed from implementation bloat
//  (VGPR 256, per-round ballot+masked loads ran every poll round; absolute
//  VALU 2.4x). All-or-nothing spin with one cheap check per round is right.
//  Changes (all proven instruction forms, protocol untouched):
//   (a) double-poll pipeline: two tag loads in flight, check round N while
//       N+1 flies -> detect quantization ~220cy -> ~110cy.
//   (b) split accumulators: acc_lo (x + kc1..5) and acc_hi (kc6..11)
//       independent, 16 final v_add -> dependency depth behind the LAST
//       arriving block halves (~-100cy tail).
//   (c) distress poll thinned to every 256 rounds (off hot path).
//  Everything else byte-identical R18: bf16 A-frag fast slab, 22-word tag
//  array w/ RELEASE-workgroup publish, publish-then-x-prefetch-then-dense,
//  distress->mirror degraded mode, depth-2 ping-pong proofs.

#define T_   512
#define F_   32
#define U_   350
#define G4   1400
#define NGRP 16
#define NB   16
#define NCB  11
#define KC   12
#define NT   88
#define HSLOTUS 5632    // ushorts per bf16 fast slot (11 blk * 512)
#define SLOTW   5632    // u32 words per mirror slot (R10 layout)

typedef __attribute__((ext_vector_type(8))) short  short8;
typedef __attribute__((ext_vector_type(4))) short  short4_;
typedef __attribute__((ext_vector_type(4))) float  float4_;
typedef unsigned long long u64t;

__device__ __forceinline__ short f2bf(float f) {
  union { float f; uint32_t u; } v; v.f = f;
  return (short)((v.u + 0x7FFFu + ((v.u >> 16) & 1u)) >> 16);
}

// ---- workspace layout (bytes) ----
#define SZ_W     (NT*KC*64*8*2u)                        // 1,081,344
#define OFF_XBF  (SZ_W)
#define SZ_XBF   (256u*T_*F_*2u)                        // 8,388,608
#define OFF_HBUF (OFF_XBF + SZ_XBF)
#define SZ_HBUF  (NGRP*2u*HSLOTUS*2u)                   // 360,448
#define OFF_HMIR (OFF_HBUF + SZ_HBUF)
#define SZ_HMIR  (NGRP*2u*SLOTW*4u)                     // 720,896
#define OFF_TAG  (OFF_HMIR + SZ_HMIR)
#define SZ_TAG   (NGRP*2u*32u*4u)                       // 4,096
#define OFF_FLG  (OFF_TAG + SZ_TAG)
#define SZ_FLG   (NGRP*16u*4u)                          // 1,024
#define OFF_WP   (OFF_FLG + SZ_FLG)
#define SZ_WP    (NGRP*NCB*NB*T_*4u)                    // 5,767,168

// ---- prep: W_swz[kc][tile][lane][8] bf16 in MFMA B-fragment order ----
__global__ void prep_w(const float* __restrict__ kern,
                       const float* __restrict__ rk,
                       const float* __restrict__ bias,
                       short* __restrict__ wswz) {
  const int tile = blockIdx.x, lane = threadIdx.x;
  const int g = tile / 22, jt = tile % 22;
  const int colg = jt * 16 + (lane & 15);
  const int src = g * U_ + colg;
  const bool valid = (colg < U_);
  const int kbase = (lane >> 4) * 8;
  for (int kc = 0; kc < KC; ++kc) {
    short8 pack;
    #pragma unroll
    for (int jj = 0; jj < 8; ++jj) {
      int k = kc * 32 + kbase + jj;
      float v = 0.f;
      if (valid) {
        if (k < F_)            v = kern[k * G4 + src];
        else if (k < F_ + U_)  v = rk[(k - F_) * G4 + src];
        else if (k == F_ + U_) v = bias[src];
      }
      pack[jj] = f2bf(v);
    }
    *(short8*)(wswz + (((size_t)kc * NT + tile) * 64 + lane) * 8) = pack;
  }
}

// ---- prep: x f32 -> bf16 ([b][t][f], contiguous 16B A-frag loads) ----
__global__ void prep_x(const float* __restrict__ x, short* __restrict__ xbf) {
  int i = (blockIdx.x * 256 + threadIdx.x) * 4;
  float4_ v = *(const float4_*)(x + i);
  short4_ o;
  #pragma unroll
  for (int jj = 0; jj < 4; ++jj) o[jj] = f2bf(v[jj]);
  *(short4_*)(xbf + i) = o;
}

// ---- init: slot1 = h_{-1}=0 tag 0 (bias col 350 = 1.0); tags; flag ----
__global__ void init_all(unsigned short* __restrict__ hb16,
                         uint32_t* __restrict__ hmir32,
                         uint32_t* __restrict__ tagbuf,
                         uint32_t* __restrict__ flagbuf) {
  int i = blockIdx.x * 256 + threadIdx.x;            // 0 .. NGRP*5632-1
  int grp = i / HSLOTUS, rem = i % HSLOTUS;
  // fast bf16 slot1: rem = blk*512 + (quad_c*16+row)*8 + cpos
  {
    int blk = rem >> 9, quadc = (rem >> 7) & 3, cpos = rem & 7;
    int col = blk * 32 + quadc * 8 + cpos;
    hb16[(size_t)(grp * 2 + 1) * HSLOTUS + rem] =
        (col == 350) ? (unsigned short)0x3F80 : 0;
  }
  // mirror slot1 (R10 tag-in-word layout)
  {
    int blkm = rem >> 8, off = rem & 255;
    int fi = blkm >> 1, fk2 = blkm & 1, fquadc = off >> 6;
    int fk1 = (off >> 1) & 1, fb = off & 1;
    int fcol = fi * 32 + fquadc * 8 + fk2 * 4 + fk1 * 2 + fb;
    hmir32[(size_t)(grp * 2 + 1) * SLOTW + rem] =
        (fcol == 350) ? 0x3F800000u : 0u;
  }
  if (rem < 32) {
    tagbuf[(size_t)(grp * 2 + 0) * 32 + rem] = 0u;
    tagbuf[(size_t)(grp * 2 + 1) * 32 + rem] = 0u;
  }
  if (rem == 0) flagbuf[grp * 16] = 0u;
}

// ---- main: persistent, 2 decoupled waves per block, weights in regs ----
__global__ __launch_bounds__(128)
__attribute__((amdgpu_waves_per_eu(1, 1)))
void lstm_kernel(const short* __restrict__ xbf, const short* __restrict__ wswz,
                 unsigned short* __restrict__ hb16, uint32_t* __restrict__ hmir32,
                 uint32_t* __restrict__ tagbuf, uint32_t* __restrict__ flagbuf,
                 const float* __restrict__ dense_w, float* __restrict__ wpart) {
  __shared__ float lds_part[2][T_][16];   // 64 KB dense-head partials

  const int tid  = threadIdx.x;
  const int lane = tid & 63;
  const int wv   = tid >> 6;            // 0..1
  const int l15  = lane & 15;
  const int quad = lane >> 4;
  const int grp  = blockIdx.x & 15;     // same-XCD heuristic (fast path only)
  const int j    = blockIdx.x >> 4;     // 0..10
  const int tileg = 2 * j + wv;         // this wave's col tile 0..21

  // weights -> registers ONCE
  short8 wreg[4][KC];
  #pragma unroll
  for (int g = 0; g < 4; ++g)
    #pragma unroll
    for (int kc = 0; kc < KC; ++kc)
      wreg[g][kc] = *(const short8*)(wswz +
          (((size_t)kc * NT + (g * 22 + tileg)) * 64 + lane) * 8);

  const int col = tileg * 16 + l15;               // gate-relative col 0..351
  const float dwv = (col < U_) ? dense_w[col] : 0.f;
  float cst[4] = {0.f, 0.f, 0.f, 0.f};

  // fast bf16 producer: ushort idx = pbase_us + r*8 (rows quad*4+r)
  const int pblk = col >> 5, pc32 = col & 31;
  const int pbase_us = pblk * 512 + ((pc32 >> 3) * 16 + quad * 4) * 8 + (pc32 & 7);
  // mirror (R10 tag-in-word) offset, +r*4 per row
  const int colrem = col & 31;
  const int fastoff = (((col >> 5) * 2 + ((colrem >> 2) & 1)) * 256)
                    + (((colrem >> 3) * 16 + quad * 4) * 4)
                    + (((colrem >> 1) & 1) * 2) + (col & 1);

  const short* xrow = xbf + ((size_t)(grp * NB + l15) * T_) * F_ + quad * 8;
  unsigned short* hbb = hb16 + (size_t)grp * 2 * HSLOTUS;
  uint32_t* hm  = hmir32 + (size_t)grp * 2 * SLOTW;
  uint32_t* tgg = tagbuf + (size_t)grp * 2 * 32;
  uint32_t* flagp = flagbuf + grp * 16;
  const int tagidx = (lane < 22) ? lane : 31;     // word31: always 0

  bool mm = false;                                 // mirror (degraded) mode
  const short hs_init = (col == 350) ? (short)0x3F80 : 0;
  uint32_t wout[4], wout_prev[4];
  #pragma unroll
  for (int r = 0; r < 4; ++r)
    wout[r] = wout_prev[r] = ((uint32_t)(unsigned short)hs_init) << 16;

  // x software pipeline prologue: load t=0 (single cold stall, once)
  short8 axf = *(const short8*)(xrow);

  #pragma unroll 1
  for (int t = 0; t < T_; ++t) {
    const uint32_t want = (uint32_t)t;
    const uint32_t* tgr = tgg + (size_t)((t + 1) & 1) * 32;
    // first tag probe (round 0) in flight before kc0 MFMAs
    uint32_t tv = __hip_atomic_load(tgr + tagidx, __ATOMIC_RELAXED,
                                    __HIP_MEMORY_SCOPE_AGENT);

    // kc=0 (x-only) MFMA — h-independent; axf loaded last iter post-publish.
    // acc_lo carries x + kc1..5; acc_hi carries kc6..11 (independent chain).
    float4_ acc_lo[4], acc_hi[4];
    #pragma unroll
    for (int g = 0; g < 4; ++g) {
      float4_ z = (float4_){0.f, 0.f, 0.f, 0.f};
      acc_lo[g] = __builtin_amdgcn_mfma_f32_16x16x32_bf16(axf, wreg[g][0], z, 0, 0, 0);
      acc_hi[g] = (float4_){0.f, 0.f, 0.f, 0.f};
    }

    short8 afr[11];
    bool gotm = false;
    bool ready = (bool)__all((int)(lane >= 22 || tv == want));
    int tries = 0;
    while (!ready) {
      // double-poll: next probe in flight while this round is checked
      uint32_t tv2 = __hip_atomic_load(tgr + tagidx, __ATOMIC_RELAXED,
                                       __HIP_MEMORY_SCOPE_AGENT);
      ++tries;
      if (!mm) {
        if ((tries & 255) == 0) {                   // poll distress (system)
          uint32_t f = __hip_atomic_load(flagp, __ATOMIC_RELAXED,
                                         __HIP_MEMORY_SCOPE_SYSTEM);
          if (f) mm = true;
        }
        if (tries == 16384) {                       // raise distress
          if (lane == 0)
            __hip_atomic_store(flagp, 1u, __ATOMIC_RELAXED,
                               __HIP_MEMORY_SCOPE_SYSTEM);
          mm = true;
        }
        if (mm) {
          // dump last two h vectors (self-validating tag-in-word)
          uint32_t* md1 = hm + (size_t)((t + 1) & 1) * SLOTW + fastoff; // tag t
          uint32_t* md0 = hm + (size_t)(t & 1) * SLOTW + fastoff;      // tag t-1
          #pragma unroll
          for (int r = 0; r < 4; ++r) {
            __hip_atomic_store(md1 + r * 4, wout[r], __ATOMIC_RELAXED,
                               __HIP_MEMORY_SCOPE_AGENT);
            __hip_atomic_store(md0 + r * 4, wout_prev[r], __ATOMIC_RELAXED,
                               __HIP_MEMORY_SCOPE_AGENT);
          }
        }
      } else {
        // mirror attempt: R10's coalesced tag-in-word path
        const u64t* mq = (const u64t*)(hm + (size_t)((t + 1) & 1) * SLOTW)
                       + (size_t)lane * 2;
        u64t q[44];
        #pragma unroll
        for (int i = 0; i < 11; ++i) {
          const u64t* pa = mq + (size_t)(2 * i) * 128;
          const u64t* pb = mq + (size_t)(2 * i + 1) * 128;
          q[4 * i + 0] = __hip_atomic_load(pa,     __ATOMIC_RELAXED, __HIP_MEMORY_SCOPE_AGENT);
          q[4 * i + 1] = __hip_atomic_load(pa + 1, __ATOMIC_RELAXED, __HIP_MEMORY_SCOPE_AGENT);
          q[4 * i + 2] = __hip_atomic_load(pb,     __ATOMIC_RELAXED, __HIP_MEMORY_SCOPE_AGENT);
          q[4 * i + 3] = __hip_atomic_load(pb + 1, __ATOMIC_RELAXED, __HIP_MEMORY_SCOPE_AGENT);
        }
        const uint32_t tag16 = want & 0xFFFFu;
        uint32_t bad = 0;
        #pragma unroll
        for (int i = 0; i < 44; ++i) {
          bad |= ((uint32_t)q[i] ^ tag16);
          bad |= ((uint32_t)(q[i] >> 32) ^ tag16);
        }
        if ((bool)__all((int)((bad & 0xFFFFu) == 0))) {
          #pragma unroll
          for (int i = 0; i < 11; ++i) {
            union { uint32_t w[4]; short8 s; } u;
            #pragma unroll
            for (int k = 0; k < 4; ++k) {
              uint32_t lo = (uint32_t)q[4 * i + k];
              uint32_t hi = (uint32_t)(q[4 * i + k] >> 32);
              u.w[k] = (lo >> 16) | (hi & 0xFFFF0000u);
            }
            afr[i] = u.s;
          }
          gotm = true;
          break;
        }
      }
      tv = tv2;                                     // pipeline shift
      ready = (bool)__all((int)(lane >= 22 || tv == want));
    }

    if (!gotm) {
      // coalesced bf16 A-frag load: lane L reads 16B at blk*1024 + L*16
      const u64t* hq = (const u64t*)(hbb + (size_t)((t + 1) & 1) * HSLOTUS)
                     + (size_t)lane * 2;
      #pragma unroll
      for (int i = 0; i < 11; ++i) {
        union { u64t q[2]; short8 s; } u;
        u.q[0] = __hip_atomic_load(hq + (size_t)i * 128,     __ATOMIC_RELAXED, __HIP_MEMORY_SCOPE_AGENT);
        u.q[1] = __hip_atomic_load(hq + (size_t)i * 128 + 1, __ATOMIC_RELAXED, __HIP_MEMORY_SCOPE_AGENT);
        afr[i] = u.s;
      }
    }

    // MFMA over kc=1..11, two independent half-chains (shorter dep tail)
    #pragma unroll
    for (int i = 0; i < 5; ++i)
      #pragma unroll
      for (int g = 0; g < 4; ++g)
        acc_lo[g] = __builtin_amdgcn_mfma_f32_16x16x32_bf16(afr[i], wreg[g][i + 1], acc_lo[g], 0, 0, 0);
    #pragma unroll
    for (int i = 5; i < 11; ++i)
      #pragma unroll
      for (int g = 0; g < 4; ++g)
        acc_hi[g] = __builtin_amdgcn_mfma_f32_16x16x32_bf16(afr[i], wreg[g][i + 1], acc_hi[g], 0, 0, 0);

    // update: lane covers rows quad*4+r at its col; gates in registers
    unsigned short* hwp = hbb + (size_t)(t & 1) * HSLOTUS + pbase_us;
    const uint32_t otag = (uint32_t)(t + 1);
    float hn[4];
    #pragma unroll
    for (int r = 0; r < 4; ++r) {
      float zi = acc_lo[0][r] + acc_hi[0][r];
      float zf = acc_lo[1][r] + acc_hi[1][r];
      float zg = acc_lo[2][r] + acc_hi[2][r];
      float zo = acc_lo[3][r] + acc_hi[3][r];
      float ig = __builtin_amdgcn_rcpf(1.f + __expf(-zi));
      float fg = __builtin_amdgcn_rcpf(1.f + __expf(-zf));
      float gg = fmaxf(zg, 0.f);
      float og = __builtin_amdgcn_rcpf(1.f + __expf(-zo));
      float cn = fg * cst[r] + ig * gg;
      cst[r] = cn;
      hn[r] = og * fmaxf(cn, 0.f);
      short hs = f2bf(hn[r]);
      if (col == 350) hs = (short)0x3F80;        // bias-row input stays 1.0
      else if (col == 351) hs = 0;
      wout_prev[r] = wout[r];
      wout[r] = (((uint32_t)(unsigned short)hs) << 16) | (otag & 0xFFFFu);
      hwp[r * 8] = (unsigned short)hs;           // fast bf16 data store (L2)
    }
    // publish tag with RELEASE (drains the 4 data stores first)
    if (lane == 0)
      __hip_atomic_store(tgg + (size_t)(t & 1) * 32 + tileg, otag,
                         __ATOMIC_RELEASE, __HIP_MEMORY_SCOPE_WORKGROUP);

    // x prefetch for t+1 POST-publish (atomic form pins placement)
    short8 axf_nx;
    {
      const int tn = (t + 1 < T_) ? (t + 1) : 0;
      const u64t* xq = (const u64t*)(xrow + tn * F_);
      union { u64t q[2]; short8 s; } ux;
      ux.q[0] = __hip_atomic_load(xq,     __ATOMIC_RELAXED, __HIP_MEMORY_SCOPE_AGENT);
      ux.q[1] = __hip_atomic_load(xq + 1, __ATOMIC_RELAXED, __HIP_MEMORY_SCOPE_AGENT);
      axf_nx = ux.s;
    }

    // degraded mode: also keep the coherent mirror current
    if (mm) {
      uint32_t* hwrm = hm + (size_t)(t & 1) * SLOTW + fastoff;
      #pragma unroll
      for (int r = 0; r < 4; ++r)
        __hip_atomic_store(hwrm + r * 4, wout[r], __ATOMIC_RELAXED,
                           __HIP_MEMORY_SCOPE_AGENT);
    }

    // dense head AFTER publish (off the recurrence; wave has slack here)
    #pragma unroll
    for (int r = 0; r < 4; ++r) {
      float s = hn[r] * dwv;
      s += __shfl_xor(s, 1); s += __shfl_xor(s, 2);
      s += __shfl_xor(s, 4); s += __shfl_xor(s, 8);
      if (l15 == 0) lds_part[wv][t][quad * 4 + r] = s;
    }

    axf = axf_nx;                                  // pipeline shift
  }

  // bulk-store dense partials (once)
  __syncthreads();
  float* wp = wpart + ((size_t)(grp * NCB + j) * NB) * T_;
  for (int i = tid; i < NB * T_; i += 128) {
    int t = i & (T_ - 1), row = i >> 9;
    wp[(size_t)row * T_ + t] = lds_part[0][t][row] + lds_part[1][t][row];
  }
}

// ---- final: out[b,t] = db + sum_j wpart[grp][j][row][t] ----
__global__ void reduce_out(const float* __restrict__ wpart,
                           const float* __restrict__ dense_b,
                           float* __restrict__ out) {
  int i = blockIdx.x * 256 + threadIdx.x;   // i = b*T + t
  int b = i >> 9, t = i & 511;
  int grp = b >> 4, row = b & 15;
  float s = dense_b[0];
  #pragma unroll
  for (int j = 0; j < NCB; ++j)
    s += wpart[(((size_t)grp * NCB + j) * NB + row) * T_ + t];
  out[i] = s;
}

extern "C" void kernel_launch(void* const* d_in, const int* in_sizes, int n_in,
                              void* d_out, int out_size, void* d_ws, size_t ws_size,
                              hipStream_t stream) {
  const float* x    = (const float*)d_in[0];
  const float* kern = (const float*)d_in[1];
  const float* rk   = (const float*)d_in[2];
  const float* bias = (const float*)d_in[3];
  const float* dw   = (const float*)d_in[4];
  const float* db   = (const float*)d_in[5];
  float* out = (float*)d_out;

  char* ws = (char*)d_ws;
  short*          wswz   = (short*)(ws);
  short*          xbf    = (short*)(ws + OFF_XBF);
  unsigned short* hb16   = (unsigned short*)(ws + OFF_HBUF);
  uint32_t*       hmir32 = (uint32_t*)(ws + OFF_HMIR);
  uint32_t*       tagbuf = (uint32_t*)(ws + OFF_TAG);
  uint32_t*       flagbuf= (uint32_t*)(ws + OFF_FLG);
  float*          wpart  = (float*)(ws + OFF_WP);

  prep_w<<<NT, 64, 0, stream>>>(kern, rk, bias, wswz);
  prep_x<<<(256 * T_ * F_) / (256 * 4), 256, 0, stream>>>(x, xbf);
  init_all<<<(NGRP * HSLOTUS) / 256, 256, 0, stream>>>(hb16, hmir32, tagbuf, flagbuf);
  lstm_kernel<<<NGRP * NCB, 128, 0, stream>>>(xbf, wswz, hb16, hmir32, tagbuf,
                                              flagbuf, dw, wpart);
  reduce_out<<<(256 * T_) / 256, 256, 0, stream>>>(wpart, db, out);
}

// Round 14
// 951.278 us; speedup vs baseline: 1.7048x; 1.1057x over previous
//
#include <hip/hip_runtime.h>
#include <stdint.h>
#include <math.h>

// LSTM B=256,T=512,F=32,U=350; gates i,f,g(relu),o; h=o*relu(c); out=h.dw+db
//
// R22: R18 verbatim (883us, best) + log2e folded into i/f/o weight tiles.
//  R21 postmortem: pipelined polling detects one round late (+230cy/step,
//  exactly measured) -> spin must check the FRESH load; R18's spin shape is
//  optimal. Split-acc bundled regression also reverted.
//  R22 change (only one, zero protocol risk): prep_w scales W and bias by
//  log2(e) for gates g in {i,f,o} (g != 2). Sigmoid becomes
//  rcp(1 + exp2(-z)) — removes the hidden mul-by-log2e inside __expf from
//  the dependent gate chain (12 v_mul/step off the recurrence). g gate
//  (relu) keeps unscaled weights.
//  Everything else byte-identical R18: bf16 A-frag fast slab (11KB), 22-word
//  tag array w/ RELEASE-workgroup publish, publish-then-x-prefetch-then-
//  dense, all-or-nothing fresh-check spin, distress->mirror degraded mode,
//  depth-2 ping-pong proofs.

#define T_   512
#define F_   32
#define U_   350
#define G4   1400
#define NGRP 16
#define NB   16
#define NCB  11
#define KC   12
#define NT   88
#define HSLOTUS 5632    // ushorts per bf16 fast slot (11 blk * 512)
#define SLOTW   5632    // u32 words per mirror slot (R10 layout)

typedef __attribute__((ext_vector_type(8))) short  short8;
typedef __attribute__((ext_vector_type(4))) short  short4_;
typedef __attribute__((ext_vector_type(4))) float  float4_;
typedef unsigned long long u64t;

__device__ __forceinline__ short f2bf(float f) {
  union { float f; uint32_t u; } v; v.f = f;
  return (short)((v.u + 0x7FFFu + ((v.u >> 16) & 1u)) >> 16);
}

// ---- workspace layout (bytes) ----
#define SZ_W     (NT*KC*64*8*2u)                        // 1,081,344
#define OFF_XBF  (SZ_W)
#define SZ_XBF   (256u*T_*F_*2u)                        // 8,388,608
#define OFF_HBUF (OFF_XBF + SZ_XBF)
#define SZ_HBUF  (NGRP*2u*HSLOTUS*2u)                   // 360,448
#define OFF_HMIR (OFF_HBUF + SZ_HBUF)
#define SZ_HMIR  (NGRP*2u*SLOTW*4u)                     // 720,896
#define OFF_TAG  (OFF_HMIR + SZ_HMIR)
#define SZ_TAG   (NGRP*2u*32u*4u)                       // 4,096
#define OFF_FLG  (OFF_TAG + SZ_TAG)
#define SZ_FLG   (NGRP*16u*4u)                          // 1,024
#define OFF_WP   (OFF_FLG + SZ_FLG)
#define SZ_WP    (NGRP*NCB*NB*T_*4u)                    // 5,767,168

// ---- prep: W_swz[kc][tile][lane][8] bf16 in MFMA B-fragment order ----
// Gates i,f,o (g != 2): W and bias pre-scaled by log2(e) so the kernel's
// sigmoid is rcp(1 + exp2(-z)) with no per-element mul.
__global__ void prep_w(const float* __restrict__ kern,
                       const float* __restrict__ rk,
                       const float* __restrict__ bias,
                       short* __restrict__ wswz) {
  const int tile = blockIdx.x, lane = threadIdx.x;
  const int g = tile / 22, jt = tile % 22;
  const int colg = jt * 16 + (lane & 15);
  const int src = g * U_ + colg;
  const bool valid = (colg < U_);
  const int kbase = (lane >> 4) * 8;
  const float scale = (g != 2) ? 1.4426950408889634f : 1.0f;
  for (int kc = 0; kc < KC; ++kc) {
    short8 pack;
    #pragma unroll
    for (int jj = 0; jj < 8; ++jj) {
      int k = kc * 32 + kbase + jj;
      float v = 0.f;
      if (valid) {
        if (k < F_)            v = kern[k * G4 + src];
        else if (k < F_ + U_)  v = rk[(k - F_) * G4 + src];
        else if (k == F_ + U_) v = bias[src];
      }
      pack[jj] = f2bf(v * scale);
    }
    *(short8*)(wswz + (((size_t)kc * NT + tile) * 64 + lane) * 8) = pack;
  }
}

// ---- prep: x f32 -> bf16 ([b][t][f], contiguous 16B A-frag loads) ----
__global__ void prep_x(const float* __restrict__ x, short* __restrict__ xbf) {
  int i = (blockIdx.x * 256 + threadIdx.x) * 4;
  float4_ v = *(const float4_*)(x + i);
  short4_ o;
  #pragma unroll
  for (int jj = 0; jj < 4; ++jj) o[jj] = f2bf(v[jj]);
  *(short4_*)(xbf + i) = o;
}

// ---- init: slot1 = h_{-1}=0 tag 0 (bias col 350 = 1.0); tags; flag ----
// Fast slot0 / mirror slot0 need no init (reads are tag-gated / tag-in-word
// poison-safe). Tag slot0 init 0 is safe: slot0 wants odd tags only.
__global__ void init_all(unsigned short* __restrict__ hb16,
                         uint32_t* __restrict__ hmir32,
                         uint32_t* __restrict__ tagbuf,
                         uint32_t* __restrict__ flagbuf) {
  int i = blockIdx.x * 256 + threadIdx.x;            // 0 .. NGRP*5632-1
  int grp = i / HSLOTUS, rem = i % HSLOTUS;
  // fast bf16 slot1: rem = blk*512 + (quad_c*16+row)*8 + cpos
  {
    int blk = rem >> 9, quadc = (rem >> 7) & 3, cpos = rem & 7;
    int col = blk * 32 + quadc * 8 + cpos;
    hb16[(size_t)(grp * 2 + 1) * HSLOTUS + rem] =
        (col == 350) ? (unsigned short)0x3F80 : 0;
  }
  // mirror slot1 (R10 tag-in-word layout)
  {
    int blkm = rem >> 8, off = rem & 255;
    int fi = blkm >> 1, fk2 = blkm & 1, fquadc = off >> 6;
    int fk1 = (off >> 1) & 1, fb = off & 1;
    int fcol = fi * 32 + fquadc * 8 + fk2 * 4 + fk1 * 2 + fb;
    hmir32[(size_t)(grp * 2 + 1) * SLOTW + rem] =
        (fcol == 350) ? 0x3F800000u : 0u;
  }
  if (rem < 32) {
    tagbuf[(size_t)(grp * 2 + 0) * 32 + rem] = 0u;
    tagbuf[(size_t)(grp * 2 + 1) * 32 + rem] = 0u;
  }
  if (rem == 0) flagbuf[grp * 16] = 0u;
}

// ---- main: persistent, 2 decoupled waves per block, weights in regs ----
__global__ __launch_bounds__(128)
__attribute__((amdgpu_waves_per_eu(1, 1)))
void lstm_kernel(const short* __restrict__ xbf, const short* __restrict__ wswz,
                 unsigned short* __restrict__ hb16, uint32_t* __restrict__ hmir32,
                 uint32_t* __restrict__ tagbuf, uint32_t* __restrict__ flagbuf,
                 const float* __restrict__ dense_w, float* __restrict__ wpart) {
  __shared__ float lds_part[2][T_][16];   // 64 KB dense-head partials

  const int tid  = threadIdx.x;
  const int lane = tid & 63;
  const int wv   = tid >> 6;            // 0..1
  const int l15  = lane & 15;
  const int quad = lane >> 4;
  const int grp  = blockIdx.x & 15;     // same-XCD heuristic (fast path only)
  const int j    = blockIdx.x >> 4;     // 0..10
  const int tileg = 2 * j + wv;         // this wave's col tile 0..21

  // weights -> registers ONCE
  short8 wreg[4][KC];
  #pragma unroll
  for (int g = 0; g < 4; ++g)
    #pragma unroll
    for (int kc = 0; kc < KC; ++kc)
      wreg[g][kc] = *(const short8*)(wswz +
          (((size_t)kc * NT + (g * 22 + tileg)) * 64 + lane) * 8);

  const int col = tileg * 16 + l15;               // gate-relative col 0..351
  const float dwv = (col < U_) ? dense_w[col] : 0.f;
  float cst[4] = {0.f, 0.f, 0.f, 0.f};

  // fast bf16 producer: ushort idx = pbase_us + r*8 (rows quad*4+r)
  const int pblk = col >> 5, pc32 = col & 31;
  const int pbase_us = pblk * 512 + ((pc32 >> 3) * 16 + quad * 4) * 8 + (pc32 & 7);
  // mirror (R10 tag-in-word) offset, +r*4 per row
  const int colrem = col & 31;
  const int fastoff = (((col >> 5) * 2 + ((colrem >> 2) & 1)) * 256)
                    + (((colrem >> 3) * 16 + quad * 4) * 4)
                    + (((colrem >> 1) & 1) * 2) + (col & 1);

  const short* xrow = xbf + ((size_t)(grp * NB + l15) * T_) * F_ + quad * 8;
  unsigned short* hbb = hb16 + (size_t)grp * 2 * HSLOTUS;
  uint32_t* hm  = hmir32 + (size_t)grp * 2 * SLOTW;
  uint32_t* tgg = tagbuf + (size_t)grp * 2 * 32;
  uint32_t* flagp = flagbuf + grp * 16;
  const int tagidx = (lane < 22) ? lane : 31;     // word31: always 0

  bool mm = false;                                 // mirror (degraded) mode
  const short hs_init = (col == 350) ? (short)0x3F80 : 0;
  uint32_t wout[4], wout_prev[4];
  #pragma unroll
  for (int r = 0; r < 4; ++r)
    wout[r] = wout_prev[r] = ((uint32_t)(unsigned short)hs_init) << 16;

  // x software pipeline prologue: load t=0 (single cold stall, once)
  short8 axf = *(const short8*)(xrow);

  #pragma unroll 1
  for (int t = 0; t < T_; ++t) {
    // first tag probe issued BEFORE kc=0 MFMAs (latency overlap)
    const uint32_t want = (uint32_t)t;
    const uint32_t* tgr = tgg + (size_t)((t + 1) & 1) * 32;
    uint32_t tv = __hip_atomic_load(tgr + tagidx, __ATOMIC_RELAXED,
                                    __HIP_MEMORY_SCOPE_AGENT);

    // kc=0 (x-only) MFMA — h-independent; axf loaded LAST iteration,
    // post-publish: its HBM latency fully drained off the vmcnt queue.
    float4_ acc[4];
    #pragma unroll
    for (int g = 0; g < 4; ++g) {
      float4_ z = (float4_){0.f, 0.f, 0.f, 0.f};
      acc[g] = __builtin_amdgcn_mfma_f32_16x16x32_bf16(axf, wreg[g][0], z, 0, 0, 0);
    }

    short8 afr[11];
    bool ready = (bool)__all((int)(lane >= 22 || tv == want));
    bool gotm = false;
    int tries = 0;
    while (!ready) {
      ++tries;
      if (!mm) {
        if ((tries & 63) == 0) {                    // poll distress (system)
          uint32_t f = __hip_atomic_load(flagp, __ATOMIC_RELAXED,
                                         __HIP_MEMORY_SCOPE_SYSTEM);
          if (f) mm = true;
        }
        if (tries == 16384) {                       // raise distress
          if (lane == 0)
            __hip_atomic_store(flagp, 1u, __ATOMIC_RELAXED,
                               __HIP_MEMORY_SCOPE_SYSTEM);
          mm = true;
        }
        if (mm) {
          // dump last two h vectors (self-validating tag-in-word)
          uint32_t* md1 = hm + (size_t)((t + 1) & 1) * SLOTW + fastoff; // tag t
          uint32_t* md0 = hm + (size_t)(t & 1) * SLOTW + fastoff;      // tag t-1
          #pragma unroll
          for (int r = 0; r < 4; ++r) {
            __hip_atomic_store(md1 + r * 4, wout[r], __ATOMIC_RELAXED,
                               __HIP_MEMORY_SCOPE_AGENT);
            __hip_atomic_store(md0 + r * 4, wout_prev[r], __ATOMIC_RELAXED,
                               __HIP_MEMORY_SCOPE_AGENT);
          }
        }
      } else {
        // mirror attempt: R10's coalesced tag-in-word path
        const u64t* mq = (const u64t*)(hm + (size_t)((t + 1) & 1) * SLOTW)
                       + (size_t)lane * 2;
        u64t q[44];
        #pragma unroll
        for (int i = 0; i < 11; ++i) {
          const u64t* pa = mq + (size_t)(2 * i) * 128;
          const u64t* pb = mq + (size_t)(2 * i + 1) * 128;
          q[4 * i + 0] = __hip_atomic_load(pa,     __ATOMIC_RELAXED, __HIP_MEMORY_SCOPE_AGENT);
          q[4 * i + 1] = __hip_atomic_load(pa + 1, __ATOMIC_RELAXED, __HIP_MEMORY_SCOPE_AGENT);
          q[4 * i + 2] = __hip_atomic_load(pb,     __ATOMIC_RELAXED, __HIP_MEMORY_SCOPE_AGENT);
          q[4 * i + 3] = __hip_atomic_load(pb + 1, __ATOMIC_RELAXED, __HIP_MEMORY_SCOPE_AGENT);
        }
        const uint32_t tag16 = want & 0xFFFFu;
        uint32_t bad = 0;
        #pragma unroll
        for (int i = 0; i < 44; ++i) {
          bad |= ((uint32_t)q[i] ^ tag16);
          bad |= ((uint32_t)(q[i] >> 32) ^ tag16);
        }
        if ((bool)__all((int)((bad & 0xFFFFu) == 0))) {
          #pragma unroll
          for (int i = 0; i < 11; ++i) {
            union { uint32_t w[4]; short8 s; } u;
            #pragma unroll
            for (int k = 0; k < 4; ++k) {
              uint32_t lo = (uint32_t)q[4 * i + k];
              uint32_t hi = (uint32_t)(q[4 * i + k] >> 32);
              u.w[k] = (lo >> 16) | (hi & 0xFFFF0000u);
            }
            afr[i] = u.s;
          }
          gotm = true;
          break;
        }
      }
      tv = __hip_atomic_load(tgr + tagidx, __ATOMIC_RELAXED,
                             __HIP_MEMORY_SCOPE_AGENT);
      ready = (bool)__all((int)(lane >= 22 || tv == want));
    }

    if (!gotm) {
      // coalesced bf16 A-frag load: lane L reads 16B at blk*1024 + L*16
      const u64t* hq = (const u64t*)(hbb + (size_t)((t + 1) & 1) * HSLOTUS)
                     + (size_t)lane * 2;
      #pragma unroll
      for (int i = 0; i < 11; ++i) {
        union { u64t q[2]; short8 s; } u;
        u.q[0] = __hip_atomic_load(hq + (size_t)i * 128,     __ATOMIC_RELAXED, __HIP_MEMORY_SCOPE_AGENT);
        u.q[1] = __hip_atomic_load(hq + (size_t)i * 128 + 1, __ATOMIC_RELAXED, __HIP_MEMORY_SCOPE_AGENT);
        afr[i] = u.s;
      }
    }

    // MFMA over kc=1..11 (no repack needed)
    #pragma unroll
    for (int i = 0; i < 11; ++i)
      #pragma unroll
      for (int g = 0; g < 4; ++g)
        acc[g] = __builtin_amdgcn_mfma_f32_16x16x32_bf16(afr[i], wreg[g][i + 1], acc[g], 0, 0, 0);

    // update: lane covers rows quad*4+r at its col; gates in registers.
    // i,f,o weights pre-scaled by log2e -> sigmoid = rcp(1 + exp2(-z)).
    unsigned short* hwp = hbb + (size_t)(t & 1) * HSLOTUS + pbase_us;
    const uint32_t otag = (uint32_t)(t + 1);
    float hn[4];
    #pragma unroll
    for (int r = 0; r < 4; ++r) {
      float ig = __builtin_amdgcn_rcpf(1.f + exp2f(-acc[0][r]));
      float fg = __builtin_amdgcn_rcpf(1.f + exp2f(-acc[1][r]));
      float gg = fmaxf(acc[2][r], 0.f);
      float og = __builtin_amdgcn_rcpf(1.f + exp2f(-acc[3][r]));
      float cn = fg * cst[r] + ig * gg;
      cst[r] = cn;
      hn[r] = og * fmaxf(cn, 0.f);
      short hs = f2bf(hn[r]);
      if (col == 350) hs = (short)0x3F80;        // bias-row input stays 1.0
      else if (col == 351) hs = 0;
      wout_prev[r] = wout[r];
      wout[r] = (((uint32_t)(unsigned short)hs) << 16) | (otag & 0xFFFFu);
      hwp[r * 8] = (unsigned short)hs;           // fast bf16 data store (L2)
    }
    // publish tag with RELEASE (drains the 4 data stores first)
    if (lane == 0)
      __hip_atomic_store(tgg + (size_t)(t & 1) * 32 + tileg, otag,
                         __ATOMIC_RELEASE, __HIP_MEMORY_SCOPE_WORKGROUP);

    // x prefetch for t+1 issued POST-publish: ~1.3kcy of lead; retires off
    // the critical path. Atomic form pins placement (no hoist across spin).
    short8 axf_nx;
    {
      const int tn = (t + 1 < T_) ? (t + 1) : 0;
      const u64t* xq = (const u64t*)(xrow + tn * F_);
      union { u64t q[2]; short8 s; } ux;
      ux.q[0] = __hip_atomic_load(xq,     __ATOMIC_RELAXED, __HIP_MEMORY_SCOPE_AGENT);
      ux.q[1] = __hip_atomic_load(xq + 1, __ATOMIC_RELAXED, __HIP_MEMORY_SCOPE_AGENT);
      axf_nx = ux.s;
    }

    // degraded mode: also keep the coherent mirror current
    if (mm) {
      uint32_t* hwrm = hm + (size_t)(t & 1) * SLOTW + fastoff;
      #pragma unroll
      for (int r = 0; r < 4; ++r)
        __hip_atomic_store(hwrm + r * 4, wout[r], __ATOMIC_RELAXED,
                           __HIP_MEMORY_SCOPE_AGENT);
    }

    // dense head AFTER publish (off the recurrence; wave has slack here)
    #pragma unroll
    for (int r = 0; r < 4; ++r) {
      float s = hn[r] * dwv;
      s += __shfl_xor(s, 1); s += __shfl_xor(s, 2);
      s += __shfl_xor(s, 4); s += __shfl_xor(s, 8);
      if (l15 == 0) lds_part[wv][t][quad * 4 + r] = s;
    }

    axf = axf_nx;                                  // pipeline shift
  }

  // bulk-store dense partials (once)
  __syncthreads();
  float* wp = wpart + ((size_t)(grp * NCB + j) * NB) * T_;
  for (int i = tid; i < NB * T_; i += 128) {
    int t = i & (T_ - 1), row = i >> 9;
    wp[(size_t)row * T_ + t] = lds_part[0][t][row] + lds_part[1][t][row];
  }
}

// ---- final: out[b,t] = db + sum_j wpart[grp][j][row][t] ----
__global__ void reduce_out(const float* __restrict__ wpart,
                           const float* __restrict__ dense_b,
                           float* __restrict__ out) {
  int i = blockIdx.x * 256 + threadIdx.x;   // i = b*T + t
  int b = i >> 9, t = i & 511;
  int grp = b >> 4, row = b & 15;
  float s = dense_b[0];
  #pragma unroll
  for (int j = 0; j < NCB; ++j)
    s += wpart[(((size_t)grp * NCB + j) * NB + row) * T_ + t];
  out[i] = s;
}

extern "C" void kernel_launch(void* const* d_in, const int* in_sizes, int n_in,
                              void* d_out, int out_size, void* d_ws, size_t ws_size,
                              hipStream_t stream) {
  const float* x    = (const float*)d_in[0];
  const float* kern = (const float*)d_in[1];
  const float* rk   = (const float*)d_in[2];
  const float* bias = (const float*)d_in[3];
  const float* dw   = (const float*)d_in[4];
  const float* db   = (const float*)d_in[5];
  float* out = (float*)d_out;

  char* ws = (char*)d_ws;
  short*          wswz   = (short*)(ws);
  short*          xbf    = (short*)(ws + OFF_XBF);
  unsigned short* hb16   = (unsigned short*)(ws + OFF_HBUF);
  uint32_t*       hmir32 = (uint32_t*)(ws + OFF_HMIR);
  uint32_t*       tagbuf = (uint32_t*)(ws + OFF_TAG);
  uint32_t*       flagbuf= (uint32_t*)(ws + OFF_FLG);
  float*          wpart  = (float*)(ws + OFF_WP);

  prep_w<<<NT, 64, 0, stream>>>(kern, rk, bias, wswz);
  prep_x<<<(256 * T_ * F_) / (256 * 4), 256, 0, stream>>>(x, xbf);
  init_all<<<(NGRP * HSLOTUS) / 256, 256, 0, stream>>>(hb16, hmir32, tagbuf, flagbuf);
  lstm_kernel<<<NGRP * NCB, 128, 0, stream>>>(xbf, wswz, hb16, hmir32, tagbuf,
                                              flagbuf, dw, wpart);
  reduce_out<<<(256 * T_) / 256, 256, 0, stream>>>(wpart, db, out);
}